// Round 1
// baseline (4806.199 us; speedup 1.0000x reference)
//
#include <hip/hip_runtime.h>

// RetinaNet 3D head: 2 heads (cls, reg) x 4 pyramid levels.
// Levels: S = 32,16,8,4 ; voxels 32768,4096,512,64 ; total 37440.
// Activation buffers: [head][level-concat][64ch][vox] fp32.

static constexpr int TOTVOX = 37440;
static constexpr int HSTRIDE = 64 * TOTVOX;          // per-head activation elems
static constexpr int CLS_TOTAL = 18 * TOTVOX;        // 673920

// ---------------------------------------------------------------------------
// Conv3d 3x3x3 SAME + bias, fused per-channel sum/sumsq (instance-norm stats).
// Grid: x = 147 spatial blocks (l0:128, l1:16, l2:2, l3:1), y = cout chunks,
// z = head. Thread: one voxel, NCO output channels.
// ---------------------------------------------------------------------------
template<int CIN, int NCO>
__global__ __launch_bounds__(256) void conv_stats_kernel(
    const float* __restrict__ q0, const float* __restrict__ q1,
    const float* __restrict__ q2, const float* __restrict__ q3,
    const float* __restrict__ src,
    const float* __restrict__ w_cls, const float* __restrict__ w_reg,
    const float* __restrict__ b_cls, const float* __restrict__ b_reg,
    float* __restrict__ dst, float* __restrict__ stats)
{
    const int head = blockIdx.z;
    const int co0  = blockIdx.y * NCO;
    const int sb   = blockIdx.x;
    int lvl, sblk;
    if (sb < 128)      { lvl = 0; sblk = sb; }
    else if (sb < 144) { lvl = 1; sblk = sb - 128; }
    else if (sb < 146) { lvl = 2; sblk = sb - 144; }
    else               { lvl = 3; sblk = 0; }
    const int ls   = 5 - lvl;
    const int S    = 1 << ls;
    const int nvox = 1 << (3 * ls);
    const int loff = (lvl == 0) ? 0 : (lvl == 1) ? 32768 : (lvl == 2) ? 36864 : 37376;

    int voxel = sblk * 256 + (int)threadIdx.x;
    const bool valid = voxel < nvox;
    if (!valid) voxel = 0;
    const int x = voxel & (S - 1);
    const int y = (voxel >> ls) & (S - 1);
    const int z = voxel >> (2 * ls);

    const float* in;
    if constexpr (CIN == 36) {
        in = (lvl == 0) ? q0 : (lvl == 1) ? q1 : (lvl == 2) ? q2 : q3;
    } else {
        in = src + head * HSTRIDE + loff * 64;
    }
    const float* w = head ? w_reg : w_cls;
    const float* b = head ? b_reg : b_cls;

    // Clamped tap addresses (always-valid loads) + multiplicative masks.
    int   addr[27];
    float msk[27];
    {
        int t = 0;
        #pragma unroll
        for (int dz = -1; dz <= 1; ++dz) {
            const int zz = z + dz;
            const bool okz = (unsigned)zz < (unsigned)S;
            const int zc = okz ? zz : (zz < 0 ? 0 : S - 1);
            #pragma unroll
            for (int dy = -1; dy <= 1; ++dy) {
                const int yy = y + dy;
                const bool oky = (unsigned)yy < (unsigned)S;
                const int yc = oky ? yy : (yy < 0 ? 0 : S - 1);
                #pragma unroll
                for (int dx = -1; dx <= 1; ++dx, ++t) {
                    const int xx = x + dx;
                    const bool okx = (unsigned)xx < (unsigned)S;
                    const int xc = okx ? xx : (xx < 0 ? 0 : S - 1);
                    addr[t] = (zc * S + yc) * S + xc;
                    msk[t]  = (okz && oky && okx) ? 1.0f : 0.0f;
                }
            }
        }
    }

    float acc[NCO];
    #pragma unroll
    for (int co = 0; co < NCO; ++co) acc[co] = b[co0 + co];

    for (int ci = 0; ci < CIN; ++ci) {
        const float* ip = in + ci * nvox;
        float v[27];
        #pragma unroll
        for (int t = 0; t < 27; ++t)
            v[t] = ip[addr[t]] * msk[t];
        const float* wp = w + (co0 * CIN + ci) * 27;   // uniform -> s_load
        #pragma unroll
        for (int co = 0; co < NCO; ++co) {
            #pragma unroll
            for (int t = 0; t < 27; ++t)
                acc[co] = fmaf(v[t], wp[co * CIN * 27 + t], acc[co]);
        }
    }

    float* dbase = dst + head * HSTRIDE + loff * 64;
    #pragma unroll
    for (int co = 0; co < NCO; ++co) {
        float s1 = valid ? acc[co] : 0.0f;
        float s2 = valid ? acc[co] * acc[co] : 0.0f;
        #pragma unroll
        for (int off = 32; off > 0; off >>= 1) {
            s1 += __shfl_xor(s1, off, 64);
            s2 += __shfl_xor(s2, off, 64);
        }
        if ((threadIdx.x & 63) == 0) {
            float* st = stats + ((head * 4 + lvl) * 64 + (co0 + co)) * 2;
            atomicAdd(st + 0, s1);
            atomicAdd(st + 1, s2);
        }
        if (valid) dbase[(co0 + co) * nvox + voxel] = acc[co];
    }
}

// ---------------------------------------------------------------------------
// InstanceNorm (affine=False) + PReLU, in-place. Grid: x=9360, y=head.
// Block-uniform level (all level-boundary elem counts divisible by 256).
// ---------------------------------------------------------------------------
__global__ __launch_bounds__(256) void norm_prelu_kernel(
    float* __restrict__ buf, const float* __restrict__ stats,
    const float* __restrict__ a_cls, const float* __restrict__ a_reg,
    const int layer)
{
    const int head = blockIdx.y;
    const int e = blockIdx.x * 256 + (int)threadIdx.x;
    int lvl;
    if (e < 2097152)      lvl = 0;
    else if (e < 2359296) lvl = 1;
    else if (e < 2392064) lvl = 2;
    else                  lvl = 3;
    const int ce   = (lvl == 0) ? 0 : (lvl == 1) ? 2097152 : (lvl == 2) ? 2359296 : 2392064;
    const int ls3  = 3 * (5 - lvl);
    const int nvox = 1 << ls3;
    const int ch   = (e - ce) >> ls3;

    const float* st = stats + ((head * 4 + lvl) * 64 + ch) * 2;
    const float inv_n = 1.0f / (float)nvox;
    const float mean = st[0] * inv_n;
    float var = st[1] * inv_n - mean * mean;
    var = fmaxf(var, 0.0f);
    const float rstd = rsqrtf(var + 1e-5f);
    const float alpha = (head ? a_reg : a_cls)[layer];

    float* p = buf + head * HSTRIDE + e;
    const float val = (*p - mean) * rstd;
    *p = (val >= 0.0f) ? val : alpha * val;
}

// ---------------------------------------------------------------------------
// Final conv3d 64 -> OUT, channel-last output directly into d_out.
// ---------------------------------------------------------------------------
template<int NCO>
__global__ __launch_bounds__(256) void final_conv_kernel(
    const float* __restrict__ src, const float* __restrict__ wf,
    const float* __restrict__ bf, float* __restrict__ out, const int OUT)
{
    const int co0 = blockIdx.y * NCO;
    const int sb  = blockIdx.x;
    int lvl, sblk;
    if (sb < 128)      { lvl = 0; sblk = sb; }
    else if (sb < 144) { lvl = 1; sblk = sb - 128; }
    else if (sb < 146) { lvl = 2; sblk = sb - 144; }
    else               { lvl = 3; sblk = 0; }
    const int ls   = 5 - lvl;
    const int S    = 1 << ls;
    const int nvox = 1 << (3 * ls);
    const int loff = (lvl == 0) ? 0 : (lvl == 1) ? 32768 : (lvl == 2) ? 36864 : 37376;

    int voxel = sblk * 256 + (int)threadIdx.x;
    const bool valid = voxel < nvox;
    if (!valid) voxel = 0;
    const int x = voxel & (S - 1);
    const int y = (voxel >> ls) & (S - 1);
    const int z = voxel >> (2 * ls);

    const float* in = src + loff * 64;

    int   addr[27];
    float msk[27];
    {
        int t = 0;
        #pragma unroll
        for (int dz = -1; dz <= 1; ++dz) {
            const int zz = z + dz;
            const bool okz = (unsigned)zz < (unsigned)S;
            const int zc = okz ? zz : (zz < 0 ? 0 : S - 1);
            #pragma unroll
            for (int dy = -1; dy <= 1; ++dy) {
                const int yy = y + dy;
                const bool oky = (unsigned)yy < (unsigned)S;
                const int yc = oky ? yy : (yy < 0 ? 0 : S - 1);
                #pragma unroll
                for (int dx = -1; dx <= 1; ++dx, ++t) {
                    const int xx = x + dx;
                    const bool okx = (unsigned)xx < (unsigned)S;
                    const int xc = okx ? xx : (xx < 0 ? 0 : S - 1);
                    addr[t] = (zc * S + yc) * S + xc;
                    msk[t]  = (okz && oky && okx) ? 1.0f : 0.0f;
                }
            }
        }
    }

    float acc[NCO];
    #pragma unroll
    for (int co = 0; co < NCO; ++co) acc[co] = bf[co0 + co];

    for (int ci = 0; ci < 64; ++ci) {
        const float* ip = in + ci * nvox;
        float v[27];
        #pragma unroll
        for (int t = 0; t < 27; ++t)
            v[t] = ip[addr[t]] * msk[t];
        const float* wp = wf + (co0 * 64 + ci) * 27;   // uniform -> s_load
        #pragma unroll
        for (int co = 0; co < NCO; ++co) {
            #pragma unroll
            for (int t = 0; t < 27; ++t)
                acc[co] = fmaf(v[t], wp[co * 64 * 27 + t], acc[co]);
        }
    }

    if (valid) {
        const long base = (long)(loff + voxel) * OUT;
        #pragma unroll
        for (int co = 0; co < NCO; ++co)
            out[base + co0 + co] = acc[co];
    }
}

// ---------------------------------------------------------------------------
extern "C" void kernel_launch(void* const* d_in, const int* in_sizes, int n_in,
                              void* d_out, int out_size, void* d_ws, size_t ws_size,
                              hipStream_t stream)
{
    const float* p0      = (const float*)d_in[0];
    const float* p1      = (const float*)d_in[1];
    const float* p2      = (const float*)d_in[2];
    const float* p3      = (const float*)d_in[3];
    const float* cls_w1  = (const float*)d_in[4];
    const float* cls_b1  = (const float*)d_in[5];
    const float* cls_w234= (const float*)d_in[6];
    const float* cls_b234= (const float*)d_in[7];
    const float* cls_a   = (const float*)d_in[8];
    const float* cls_wf  = (const float*)d_in[9];
    const float* cls_bf  = (const float*)d_in[10];
    const float* reg_w1  = (const float*)d_in[11];
    const float* reg_b1  = (const float*)d_in[12];
    const float* reg_w234= (const float*)d_in[13];
    const float* reg_b234= (const float*)d_in[14];
    const float* reg_a   = (const float*)d_in[15];
    const float* reg_wf  = (const float*)d_in[16];
    const float* reg_bf  = (const float*)d_in[17];

    float* ws    = (float*)d_ws;
    float* stats = ws;                 // 4 layers * 2 heads * 4 lvl * 64 ch * 2 = 4096 floats
    float* bufA  = ws + 4096;          // 2 * HSTRIDE
    float* bufB  = bufA + 2 * HSTRIDE; // 2 * HSTRIDE

    hipMemsetAsync(stats, 0, 4096 * sizeof(float), stream);

    const dim3 cgrid(147, 4, 2);   // 64 cout / 16
    const dim3 ngrid(9360, 2);

    // layer 0: 36 -> 64
    conv_stats_kernel<36, 16><<<cgrid, 256, 0, stream>>>(
        p0, p1, p2, p3, nullptr, cls_w1, reg_w1, cls_b1, reg_b1, bufA, stats);
    norm_prelu_kernel<<<ngrid, 256, 0, stream>>>(bufA, stats, cls_a, reg_a, 0);

    // layers 1..3: 64 -> 64, ping-pong A->B->A->B
    float* srcs[3] = { bufA, bufB, bufA };
    float* dsts[3] = { bufB, bufA, bufB };
    for (int l = 0; l < 3; ++l) {
        const float* wc = cls_w234 + l * 64 * 64 * 27;
        const float* wr = reg_w234 + l * 64 * 64 * 27;
        const float* bc = cls_b234 + l * 64;
        const float* br = reg_b234 + l * 64;
        float* st = stats + (l + 1) * 1024;
        conv_stats_kernel<64, 16><<<cgrid, 256, 0, stream>>>(
            nullptr, nullptr, nullptr, nullptr, srcs[l], wc, wr, bc, br, dsts[l], st);
        norm_prelu_kernel<<<ngrid, 256, 0, stream>>>(dsts[l], st, cls_a, reg_a, l + 1);
    }

    // final convs (from bufB): cls 64->18, reg 64->54, channel-last into d_out
    float* outf = (float*)d_out;
    final_conv_kernel<9><<<dim3(147, 2), 256, 0, stream>>>(bufB, cls_wf, cls_bf, outf, 18);
    final_conv_kernel<9><<<dim3(147, 6), 256, 0, stream>>>(bufB + HSTRIDE, reg_wf, reg_bf, outf + CLS_TOTAL, 54);
}